// Round 1
// baseline (958.204 us; speedup 1.0000x reference)
//
#include <hip/hip_runtime.h>

#define NB 2
#define NN 4096
#define DIMD 512
#define PD 64
#define KNN 16
#define MROWS (NB*NN)  // 8192

// ---------------- kernel 1: flow (f64) + new_pos + row sq-norm ----------------
__global__ __launch_bounds__(256)
void flow_kernel(const float* __restrict__ states, const float* __restrict__ positions,
                 const float* __restrict__ W_flow, const float* __restrict__ b_flow,
                 float* __restrict__ out_np, float* __restrict__ out_fl,
                 double* __restrict__ npos64, double* __restrict__ sq64)
{
    __shared__ float s_lds[4][DIMD];
    const int t = threadIdx.x;
    const int row0 = blockIdx.x * 4;
    // stage 4 state rows (2048 floats = 512 float4), coalesced
    const float4* src = (const float4*)(states + (size_t)row0 * DIMD);
    float4* dst = (float4*)&s_lds[0][0];
    dst[t] = src[t];
    dst[t + 256] = src[t + 256];
    __syncthreads();
    const int lr = t >> 6;      // local row 0..3 (one wave per row)
    const int p  = t & 63;      // output dim
    const int row = row0 + lr;
    const float4* wr = (const float4*)(W_flow + (size_t)p * DIMD);
    const float4* sr = (const float4*)&s_lds[lr][0];
    double acc = 0.0;
    #pragma unroll 8
    for (int d4 = 0; d4 < DIMD/4; ++d4) {
        float4 w4 = wr[d4];
        float4 s4 = sr[d4];
        acc += (double)s4.x * (double)w4.x;
        acc += (double)s4.y * (double)w4.y;
        acc += (double)s4.z * (double)w4.z;
        acc += (double)s4.w * (double)w4.w;
    }
    acc += (double)b_flow[p];
    const size_t g = (size_t)row * PD + p;
    double np_ = (double)positions[g] + 0.1 * acc;
    out_fl[g] = (float)acc;
    out_np[g] = (float)np_;
    npos64[g] = np_;
    double s2 = np_ * np_;
    #pragma unroll
    for (int off = 32; off >= 1; off >>= 1) s2 += __shfl_xor(s2, off);
    if (p == 0) sq64[row] = s2;
}

// ---------------- kernel 2: values = states @ W_val^T + b_val (f32 tiled) ----------------
__global__ __launch_bounds__(256)
void values_gemm(const float* __restrict__ A, const float* __restrict__ W,
                 const float* __restrict__ bias, float* __restrict__ C)
{
    __shared__ float As[16][68];
    __shared__ float Bs[16][68];
    const int t = threadIdx.x;
    const int bm = blockIdx.y, bn = blockIdx.x;
    const int lr  = t >> 2;          // 0..63 tile row for loads
    const int lc4 = (t & 3) << 2;    // k offset 0,4,8,12
    const int cr = (t >> 4) << 2;    // compute rows base
    const int cc = (t & 15) << 2;    // compute cols base
    float acc[4][4] = {};
    for (int k0 = 0; k0 < DIMD; k0 += 16) {
        float4 av = *(const float4*)(A + (size_t)(bm*64 + lr)*DIMD + k0 + lc4);
        float4 wv = *(const float4*)(W + (size_t)(bn*64 + lr)*DIMD + k0 + lc4);
        __syncthreads();
        As[lc4+0][lr] = av.x; As[lc4+1][lr] = av.y; As[lc4+2][lr] = av.z; As[lc4+3][lr] = av.w;
        Bs[lc4+0][lr] = wv.x; Bs[lc4+1][lr] = wv.y; Bs[lc4+2][lr] = wv.z; Bs[lc4+3][lr] = wv.w;
        __syncthreads();
        #pragma unroll
        for (int kk = 0; kk < 16; ++kk) {
            float4 a  = *(const float4*)&As[kk][cr];
            float4 b4 = *(const float4*)&Bs[kk][cc];
            acc[0][0] += a.x*b4.x; acc[0][1] += a.x*b4.y; acc[0][2] += a.x*b4.z; acc[0][3] += a.x*b4.w;
            acc[1][0] += a.y*b4.x; acc[1][1] += a.y*b4.y; acc[1][2] += a.y*b4.z; acc[1][3] += a.y*b4.w;
            acc[2][0] += a.z*b4.x; acc[2][1] += a.z*b4.y; acc[2][2] += a.z*b4.z; acc[2][3] += a.z*b4.w;
            acc[3][0] += a.w*b4.x; acc[3][1] += a.w*b4.y; acc[3][2] += a.w*b4.z; acc[3][3] += a.w*b4.w;
        }
    }
    const int colb = bn*64 + cc;
    float4 bb = *(const float4*)(bias + colb);
    #pragma unroll
    for (int i = 0; i < 4; ++i) {
        float4 o;
        o.x = acc[i][0] + bb.x;
        o.y = acc[i][1] + bb.y;
        o.z = acc[i][2] + bb.z;
        o.w = acc[i][3] + bb.w;
        *(float4*)(C + (size_t)(bm*64 + cr + i)*DIMD + colb) = o;
    }
}

// ---------------- kernel 3: distances (f64) + exact top-16 + context ----------------
__device__ __forceinline__ bool lexless(double v, int i, double w, int j) {
    return (v < w) || (v == w && i < j);
}

__device__ __forceinline__ void tk_insert(double (&bv)[16], int (&bi)[16], double v, int i) {
    if (lexless(v, i, bv[15], bi[15])) {
        bv[15] = v; bi[15] = i;
        #pragma unroll
        for (int k = 15; k > 0; --k) {
            if (lexless(bv[k], bi[k], bv[k-1], bi[k-1])) {
                double tv = bv[k]; bv[k] = bv[k-1]; bv[k-1] = tv;
                int ti = bi[k]; bi[k] = bi[k-1]; bi[k-1] = ti;
            }
        }
    }
}

__device__ __forceinline__ void merge_emit(double (&bv)[16], int (&bi)[16], int lane,
                                           int* ix_row, float* w_row)
{
    double wsum = 0.0, mywgt = 0.0;
    for (int k = 0; k < KNN; ++k) {
        double v = bv[0]; int i = bi[0];
        #pragma unroll
        for (int off = 32; off >= 1; off >>= 1) {
            double ov = __shfl_xor(v, off);
            int    oi = __shfl_xor(i, off);
            if (lexless(ov, oi, v, i)) { v = ov; i = oi; }
        }
        // the (unique) winning lane pops its head
        if (bi[0] == i) {
            #pragma unroll
            for (int k2 = 0; k2 < 15; ++k2) { bv[k2] = bv[k2+1]; bi[k2] = bi[k2+1]; }
            bv[15] = 1e300; bi[15] = 0x7fffffff;
        }
        double d  = sqrt(fmax(v, 1e-12));
        double wk = exp(-0.5 * d);   // exp(-d/(2*sigma^2)), sigma=1
        wsum += wk;
        if (lane == k) mywgt = wk;
        if (lane == 0) ix_row[k] = i;
    }
    double den = wsum + 1e-8;
    if (lane < KNN) w_row[lane] = (float)(mywgt / den);
}

__global__ __launch_bounds__(512)
void dist_kernel(const double* __restrict__ npos64, const double* __restrict__ sq64,
                 const float* __restrict__ values, float* __restrict__ ctx)
{
    __shared__ double pbuf[64][66];   // [p][r], pad 66 -> 2-way (free) bank pattern on reads
    __shared__ double sqc[64];
    __shared__ int   tk_ix[16][16];
    __shared__ float tk_w[16][16];
    const int tid  = threadIdx.x;
    const int w    = tid >> 6;        // wave id 0..7
    const int lane = tid & 63;
    const int b  = blockIdx.x >> 8;           // 256 blocks per batch
    const int n0 = (blockIdx.x & 255) << 4;   // 16 queries per block
    const double* P = npos64 + (size_t)b * NN * PD;
    const int nqA = n0 + 2*w, nqB = nqA + 1;
    const double* qra = P + (size_t)nqA * PD;   // wave-uniform address -> scalar loads
    const double* qrb = P + (size_t)nqB * PD;
    const double sqnA = sq64[b*NN + nqA];
    const double sqnB = sq64[b*NN + nqB];

    double bvA[16], bvB[16]; int biA[16], biB[16];
    #pragma unroll
    for (int k = 0; k < 16; ++k) { bvA[k]=1e300; bvB[k]=1e300; biA[k]=0x7fffffff; biB[k]=0x7fffffff; }

    for (int c = 0; c < NN; c += 64) {
        __syncthreads();
        // stage 64 rows x 64 doubles (transposed [p][r]); coalesced global double2 reads
        #pragma unroll
        for (int j0 = 0; j0 < 4; ++j0) {
            int j = tid + j0*512;      // 0..2047 double2 index
            int r = j >> 5, p2 = j & 31;
            double2 v = *(const double2*)(P + (size_t)(c + r) * PD + p2*2);
            pbuf[2*p2][r]   = v.x;
            pbuf[2*p2+1][r] = v.y;
        }
        if (tid < 64) sqc[tid] = sq64[b*NN + c + tid];
        __syncthreads();

        double accA = 0.0, accB = 0.0;
        #pragma unroll 8
        for (int p = 0; p < 64; ++p) {
            double pv = pbuf[p][lane];
            accA += qra[p] * pv;
            accB += qrb[p] * pv;
        }
        const int m = c + lane;
        double d2A = sqnA + sqc[lane] - 2.0*accA;
        double d2B = sqnB + sqc[lane] - 2.0*accB;
        if (m == nqA) d2A = 1e30;   // exclude self
        if (m == nqB) d2B = 1e30;
        tk_insert(bvA, biA, d2A, m);
        tk_insert(bvB, biB, d2B, m);
    }

    merge_emit(bvA, biA, lane, tk_ix[2*w],   tk_w[2*w]);
    merge_emit(bvB, biB, lane, tk_ix[2*w+1], tk_w[2*w+1]);
    __syncthreads();

    // context: 16 queries x 512 dims; thread -> (q, 16 dims)
    const int q  = tid >> 5;
    const int e0 = (tid & 31) << 4;
    const float* V = values + (size_t)b * NN * DIMD;
    float acc[16] = {};
    for (int k = 0; k < KNN; ++k) {
        int   m  = tk_ix[q][k];
        float wg = tk_w[q][k];
        const float4* vr = (const float4*)(V + (size_t)m * DIMD + e0);
        #pragma unroll
        for (int j = 0; j < 4; ++j) {
            float4 vv = vr[j];
            acc[4*j+0] += wg*vv.x; acc[4*j+1] += wg*vv.y;
            acc[4*j+2] += wg*vv.z; acc[4*j+3] += wg*vv.w;
        }
    }
    float* crow = ctx + (size_t)(b*NN + n0 + q) * DIMD + e0;
    #pragma unroll
    for (int j = 0; j < 4; ++j) {
        *(float4*)(crow + 4*j) = make_float4(acc[4*j], acc[4*j+1], acc[4*j+2], acc[4*j+3]);
    }
}

extern "C" void kernel_launch(void* const* d_in, const int* in_sizes, int n_in,
                              void* d_out, int out_size, void* d_ws, size_t ws_size,
                              hipStream_t stream)
{
    (void)in_sizes; (void)n_in; (void)out_size; (void)ws_size;
    const float* states    = (const float*)d_in[0];
    const float* positions = (const float*)d_in[1];
    const float* W_flow    = (const float*)d_in[2];
    const float* b_flow    = (const float*)d_in[3];
    const float* W_val     = (const float*)d_in[4];
    const float* b_val     = (const float*)d_in[5];

    float* out_ctx = (float*)d_out;                       // [B,N,DIM]
    float* out_np  = out_ctx + (size_t)NB*NN*DIMD;        // [B,N,PD]
    float* out_fl  = out_np  + (size_t)NB*NN*PD;          // [B,N,PD]

    float*  values_ws = (float*)d_ws;                                       // 16 MB
    double* npos64    = (double*)((char*)d_ws + (size_t)NB*NN*DIMD*4);      // 4 MB
    double* sq64      = (double*)((char*)npos64 + (size_t)NB*NN*PD*8);      // 64 KB

    hipLaunchKernelGGL(flow_kernel, dim3(MROWS/4), dim3(256), 0, stream,
                       states, positions, W_flow, b_flow, out_np, out_fl, npos64, sq64);
    hipLaunchKernelGGL(values_gemm, dim3(DIMD/64, MROWS/64), dim3(256), 0, stream,
                       states, W_val, b_val, values_ws);
    hipLaunchKernelGGL(dist_kernel, dim3(512), dim3(512), 0, stream,
                       npos64, sq64, values_ws, out_ctx);
}